// Round 2
// baseline (336.878 us; speedup 1.0000x reference)
//
#include <hip/hip_runtime.h>
#include <math.h>

#define ACC_BITS 23

// Scale-decomposition parameters, computed once on device (scalars are device
// memory, so this can't be host-side). Stored in d_ws.
struct QParams {
    float     scale;
    int       nm_x, e_x, nm_i, e_i;
    long long nm_x64, nm_i64;       // for the generic fallback path
};

__global__ void qparams_kernel(const float* __restrict__ pre_sf,
                               const float* __restrict__ id_sf,
                               const float* __restrict__ xminp,
                               const float* __restrict__ xmaxp,
                               QParams* __restrict__ p,
                               float* __restrict__ out_scale)
{
    float s = fmaxf(fmaxf(fabsf(xminp[0]), fabsf(xmaxp[0])), 1e-8f); // clip(max(|min|,|max|),1e-8)
    float scale = s / 127.0f;            // fp32 divide, bit-exact vs reference

    double s64  = (double)scale;
    double ns_x = (double)pre_sf[0] / s64;
    double ns_i = (double)id_sf[0] / s64;

    int e_x, e_i;
    double m_x = frexp(ns_x, &e_x);      // m in [0.5,1)
    double m_i = frexp(ns_i, &e_i);
    long long nm_x = (long long)rint(m_x * 8388608.0);   // round-half-even == jnp.round
    long long nm_i = (long long)rint(m_i * 8388608.0);

    p->scale = scale;
    p->nm_x = (int)nm_x;  p->e_x = e_x;
    p->nm_i = (int)nm_i;  p->e_i = e_i;
    p->nm_x64 = nm_x;     p->nm_i64 = nm_i;
    *out_scale = scale;                  // tuple output 1
}

// Generic bit-exact replica (fallback + tail only).
__device__ __forceinline__ long long fixed_point_mul64(long long xi, long long nm, int e) {
    long long tmp = xi * nm;
    if (e - ACC_BITS >= 0) {
        return tmp << (e - ACC_BITS);
    } else {
        int sr = ACC_BITS - e;
        long long nudge = (1LL << (sr - 1)) - (long long)(tmp < 0);
        return (tmp + nudge) >> sr;
    }
}

typedef float f32x4 __attribute__((ext_vector_type(4)));

__global__ void __launch_bounds__(256)
quantact_main(const f32x4* __restrict__ x,
              const f32x4* __restrict__ idn,
              f32x4* __restrict__ out,
              const QParams* __restrict__ p,
              int n4, int n)
{
    const float scale = p->scale;
    const int nm_x = p->nm_x, nm_i = p->nm_i;
    const int e_x  = p->e_x,  e_i  = p->e_i;
    const int sr_x = ACC_BITS - e_x, sr_i = ACC_BITS - e_i;

    const int tid    = blockIdx.x * blockDim.x + threadIdx.x;
    const int stride = gridDim.x * blockDim.x;

    // Fast path preconditions (true for any sane positive scales):
    // nm > 0 so sign(x*nm) == sign(x); right-shift branch with sr in [1,62].
    const bool fast = (nm_x > 0) & (nm_i > 0) &
                      (sr_x >= 1) & (sr_x <= 62) & (sr_i >= 1) & (sr_i <= 62);

    if (fast) {
        const long long Kx = 1LL << (sr_x - 1);   // uniform round nudge bases
        const long long Ki = 1LL << (sr_i - 1);

        int i = tid;
        // 2-wide manual unroll: 4 loads in flight before the ALU chain.
        for (; i + stride < n4; i += 2 * stride) {
            f32x4 xv0 = x[i];
            f32x4 iv0 = idn[i];
            f32x4 xv1 = x[i + stride];
            f32x4 iv1 = idn[i + stride];
            f32x4 ov0, ov1;
            #pragma unroll
            for (int c = 0; c < 4; ++c) {
                {
                    int xi = (int)xv0[c];
                    int ii = (int)iv0[c];
                    // mad_i64_i32 + sub64: (x*nm + K) - (x<0)
                    long long tx = (long long)xi * nm_x + Kx - (long long)((unsigned)xi >> 31);
                    long long ti = (long long)ii * nm_i + Ki - (long long)((unsigned)ii >> 31);
                    long long o  = (tx >> sr_x) + (ti >> sr_i);
                    int lo = (int)o, hi = (int)(o >> 32);
                    int cl  = lo < -128 ? -128 : (lo > 127 ? 127 : lo);  // v_med3_i32
                    int sat = hi < 0 ? -128 : 127;
                    int q   = (hi == (lo >> 31)) ? cl : sat;             // i64 overflow fixup
                    ov0[c] = (float)q * scale;
                }
                {
                    int xi = (int)xv1[c];
                    int ii = (int)iv1[c];
                    long long tx = (long long)xi * nm_x + Kx - (long long)((unsigned)xi >> 31);
                    long long ti = (long long)ii * nm_i + Ki - (long long)((unsigned)ii >> 31);
                    long long o  = (tx >> sr_x) + (ti >> sr_i);
                    int lo = (int)o, hi = (int)(o >> 32);
                    int cl  = lo < -128 ? -128 : (lo > 127 ? 127 : lo);
                    int sat = hi < 0 ? -128 : 127;
                    int q   = (hi == (lo >> 31)) ? cl : sat;
                    ov1[c] = (float)q * scale;
                }
            }
            __builtin_nontemporal_store(ov0, &out[i]);
            __builtin_nontemporal_store(ov1, &out[i + stride]);
        }
        for (; i < n4; i += stride) {
            f32x4 xv = x[i];
            f32x4 iv = idn[i];
            f32x4 ov;
            #pragma unroll
            for (int c = 0; c < 4; ++c) {
                int xi = (int)xv[c];
                int ii = (int)iv[c];
                long long tx = (long long)xi * nm_x + Kx - (long long)((unsigned)xi >> 31);
                long long ti = (long long)ii * nm_i + Ki - (long long)((unsigned)ii >> 31);
                long long o  = (tx >> sr_x) + (ti >> sr_i);
                int lo = (int)o, hi = (int)(o >> 32);
                int cl  = lo < -128 ? -128 : (lo > 127 ? 127 : lo);
                int sat = hi < 0 ? -128 : 127;
                int q   = (hi == (lo >> 31)) ? cl : sat;
                ov[c] = (float)q * scale;
            }
            __builtin_nontemporal_store(ov, &out[i]);
        }
    } else {
        // Generic path: exact replica of the reference branches.
        const long long nm64_x = p->nm_x64, nm64_i = p->nm_i64;
        for (int i = tid; i < n4; i += stride) {
            f32x4 xv = x[i];
            f32x4 iv = idn[i];
            f32x4 ov;
            #pragma unroll
            for (int c = 0; c < 4; ++c) {
                long long o = fixed_point_mul64((long long)xv[c], nm64_x, e_x)
                            + fixed_point_mul64((long long)iv[c], nm64_i, e_i);
                o = o < -128 ? -128 : (o > 127 ? 127 : o);
                ov[c] = (float)(int)o * scale;
            }
            out[i] = ov;
        }
    }

    // scalar tail for n % 4 != 0 (not hit at this shape)
    const float* xs  = (const float*)x;
    const float* is_ = (const float*)idn;
    float* os = (float*)out;
    const long long nm64_x = p->nm_x64, nm64_i = p->nm_i64;
    for (int j = n4 * 4 + tid; j < n; j += stride) {
        long long o = fixed_point_mul64((long long)xs[j], nm64_x, e_x)
                    + fixed_point_mul64((long long)is_[j], nm64_i, e_i);
        o = o < -128 ? -128 : (o > 127 ? 127 : o);
        os[j] = (float)(int)o * scale;
    }
}

extern "C" void kernel_launch(void* const* d_in, const int* in_sizes, int n_in,
                              void* d_out, int out_size, void* d_ws, size_t ws_size,
                              hipStream_t stream) {
    const f32x4* x      = (const f32x4*)d_in[0];
    const f32x4* idn    = (const f32x4*)d_in[1];
    const float* pre_sf = (const float*)d_in[2];
    const float* id_sf  = (const float*)d_in[3];
    const float* xmin   = (const float*)d_in[4];
    const float* xmax   = (const float*)d_in[5];

    int n  = in_sizes[0];          // 33,554,432
    int n4 = n / 4;

    float* out       = (float*)d_out;
    float* out_scale = out + n;    // tuple output 1 (flat-concatenated)
    QParams* p       = (QParams*)d_ws;

    qparams_kernel<<<1, 1, 0, stream>>>(pre_sf, id_sf, xmin, xmax, p, out_scale);

    const int block = 256;
    int grid = 4096;               // 1M threads, 8 float4/thread
    int max_grid = (n4 + block - 1) / block;
    if (grid > max_grid) grid = max_grid;
    if (grid < 1) grid = 1;

    quantact_main<<<grid, block, 0, stream>>>(x, idn, (f32x4*)out, p, n4, n);
}

// Round 3
// 329.025 us; speedup vs baseline: 1.0239x; 1.0239x over previous
//
#include <hip/hip_runtime.h>
#include <math.h>

#define ACC_BITS 23

// Params computed once on-device (scalar inputs live in device memory).
struct QParams {
    float scale;
    int   fast;                       // 1 => 24-bit fast path valid
    int   nmx_hi, nmx_lo, Kx, srx12;  // x:  nm split 12/12, K=2^(sr-1), sr-12
    int   nmi_hi, nmi_lo, Ki, sri12;  // id: same
    long long nm_x64, nm_i64;         // generic fallback
    int   e_x, e_i;
};

__global__ void qparams_kernel(const float* __restrict__ pre_sf,
                               const float* __restrict__ id_sf,
                               const float* __restrict__ xminp,
                               const float* __restrict__ xmaxp,
                               QParams* __restrict__ p,
                               float* __restrict__ out_scale)
{
    float s = fmaxf(fmaxf(fabsf(xminp[0]), fabsf(xmaxp[0])), 1e-8f);
    float scale = s / 127.0f;                 // fp32 divide, bit-exact vs reference

    double s64  = (double)scale;
    double ns_x = (double)pre_sf[0] / s64;
    double ns_i = (double)id_sf[0] / s64;

    int e_x, e_i;
    double m_x = frexp(ns_x, &e_x);           // m in [0.5,1)
    double m_i = frexp(ns_i, &e_i);
    long long nm_x = (long long)rint(m_x * 8388608.0);   // round-half-even == jnp.round
    long long nm_i = (long long)rint(m_i * 8388608.0);

    p->scale  = scale;
    p->nm_x64 = nm_x;  p->e_x = e_x;
    p->nm_i64 = nm_i;  p->e_i = e_i;

    // Normalize nm == 2^23 -> (2^22, e+1). Result-identical: the rounded
    // numerator xi*nm + 2^(sr-1) is always even, so the -bit nudge cannot
    // cross a floor boundary differently between the two encodings.
    long long ax = nm_x, ai = nm_i;
    int ex = e_x, ei = e_i;
    if (ax == (1LL << 23)) { ax >>= 1; ex += 1; }
    if (ai == (1LL << 23)) { ai >>= 1; ei += 1; }
    int sr_x = ACC_BITS - ex, sr_i = ACC_BITS - ei;

    // Fast path: nm fits i24 (positive, < 2^23), 12 <= sr <= 30 so that
    // K = 2^(sr-1) fits i32 and the 12/12 shift split applies.
    int fast = (ax > 0) && (ax < (1LL << 23)) &&
               (ai > 0) && (ai < (1LL << 23)) &&
               (sr_x >= 12) && (sr_x <= 30) && (sr_i >= 12) && (sr_i <= 30);
    p->fast = fast;
    p->nmx_hi = (int)(ax >> 12); p->nmx_lo = (int)(ax & 0xFFF);
    p->nmi_hi = (int)(ai >> 12); p->nmi_lo = (int)(ai & 0xFFF);
    p->Kx = fast ? (1 << (sr_x - 1)) : 0;
    p->Ki = fast ? (1 << (sr_i - 1)) : 0;
    p->srx12 = sr_x - 12;
    p->sri12 = sr_i - 12;

    *out_scale = scale;                       // tuple output 1
}

// Generic bit-exact replica (fallback + tail).
__device__ __forceinline__ long long fixed_point_mul64(long long xi, long long nm, int e) {
    long long tmp = xi * nm;
    if (e - ACC_BITS >= 0) {
        return tmp << (e - ACC_BITS);
    } else {
        int sr = ACC_BITS - e;
        long long nudge = (1LL << (sr - 1)) - (long long)(tmp < 0);
        return (tmp + nudge) >> sr;
    }
}

// Full-rate 24-bit-multiply fixed-point mul. Exact replica of
// (xi*nm + 2^(sr-1) - (xi<0)) >> sr  for |xi| < 2^19, 0 < nm < 2^23, 12<=sr<=30:
//   xi*nm = (xi*nm_hi)<<12 + xi*nm_lo   (both partials full-rate v_mul/mad_i32_i24)
//   (A<<12 + B) >> sr == (A + (B>>12)) >> (sr-12)   (arithmetic shifts compose)
__device__ __forceinline__ int fpm24(int xi, int nm_hi, int nm_lo, int K, int sr12) {
    int bit = (int)((unsigned)xi >> 31);
    int B = (__mul24(xi, nm_lo) + K - bit) >> 12;   // v_mad_i32_i24 + sub + ashr
    int A = __mul24(xi, nm_hi);
    return (A + B) >> sr12;
}

typedef float f32x4 __attribute__((ext_vector_type(4)));

__global__ void __launch_bounds__(256)
quantact_main(const f32x4* __restrict__ x,
              const f32x4* __restrict__ idn,
              f32x4* __restrict__ out,
              const QParams* __restrict__ p,
              int n4, int n)
{
    const float scale = p->scale;
    const int tid    = blockIdx.x * blockDim.x + threadIdx.x;
    const int stride = gridDim.x * blockDim.x;

    if (p->fast) {
        const int nmx_hi = p->nmx_hi, nmx_lo = p->nmx_lo, Kx = p->Kx, srx = p->srx12;
        const int nmi_hi = p->nmi_hi, nmi_lo = p->nmi_lo, Ki = p->Ki, sri = p->sri12;

        int i = tid;
        for (; i + stride < n4; i += 2 * stride) {     // 4 loads in flight
            f32x4 xv0 = x[i];
            f32x4 iv0 = idn[i];
            f32x4 xv1 = x[i + stride];
            f32x4 iv1 = idn[i + stride];
            f32x4 ov0, ov1;
            #pragma unroll
            for (int c = 0; c < 4; ++c) {
                int o0 = fpm24((int)xv0[c], nmx_hi, nmx_lo, Kx, srx)
                       + fpm24((int)iv0[c], nmi_hi, nmi_lo, Ki, sri);
                o0 = o0 < -128 ? -128 : (o0 > 127 ? 127 : o0);   // v_med3_i32
                ov0[c] = (float)o0 * scale;
                int o1 = fpm24((int)xv1[c], nmx_hi, nmx_lo, Kx, srx)
                       + fpm24((int)iv1[c], nmi_hi, nmi_lo, Ki, sri);
                o1 = o1 < -128 ? -128 : (o1 > 127 ? 127 : o1);
                ov1[c] = (float)o1 * scale;
            }
            out[i] = ov0;                               // plain stores (nt regressed: R2)
            out[i + stride] = ov1;
        }
        for (; i < n4; i += stride) {
            f32x4 xv = x[i];
            f32x4 iv = idn[i];
            f32x4 ov;
            #pragma unroll
            for (int c = 0; c < 4; ++c) {
                int o = fpm24((int)xv[c], nmx_hi, nmx_lo, Kx, srx)
                      + fpm24((int)iv[c], nmi_hi, nmi_lo, Ki, sri);
                o = o < -128 ? -128 : (o > 127 ? 127 : o);
                ov[c] = (float)o * scale;
            }
            out[i] = ov;
        }
    } else {
        // Generic path: exact 64-bit replica of the reference branches.
        const long long nm64_x = p->nm_x64, nm64_i = p->nm_i64;
        const int e_x = p->e_x, e_i = p->e_i;
        for (int i = tid; i < n4; i += stride) {
            f32x4 xv = x[i];
            f32x4 iv = idn[i];
            f32x4 ov;
            #pragma unroll
            for (int c = 0; c < 4; ++c) {
                long long o = fixed_point_mul64((long long)xv[c], nm64_x, e_x)
                            + fixed_point_mul64((long long)iv[c], nm64_i, e_i);
                o = o < -128 ? -128 : (o > 127 ? 127 : o);
                ov[c] = (float)(int)o * scale;
            }
            out[i] = ov;
        }
    }

    // scalar tail for n % 4 != 0 (not hit at this shape)
    {
        const float* xs  = (const float*)x;
        const float* is_ = (const float*)idn;
        float* os = (float*)out;
        const long long nm64_x = p->nm_x64, nm64_i = p->nm_i64;
        const int e_x = p->e_x, e_i = p->e_i;
        for (int j = n4 * 4 + tid; j < n; j += stride) {
            long long o = fixed_point_mul64((long long)xs[j], nm64_x, e_x)
                        + fixed_point_mul64((long long)is_[j], nm64_i, e_i);
            o = o < -128 ? -128 : (o > 127 ? 127 : o);
            os[j] = (float)(int)o * scale;
        }
    }
}

extern "C" void kernel_launch(void* const* d_in, const int* in_sizes, int n_in,
                              void* d_out, int out_size, void* d_ws, size_t ws_size,
                              hipStream_t stream) {
    const f32x4* x      = (const f32x4*)d_in[0];
    const f32x4* idn    = (const f32x4*)d_in[1];
    const float* pre_sf = (const float*)d_in[2];
    const float* id_sf  = (const float*)d_in[3];
    const float* xmin   = (const float*)d_in[4];
    const float* xmax   = (const float*)d_in[5];

    int n  = in_sizes[0];          // 33,554,432
    int n4 = n / 4;

    float* out       = (float*)d_out;
    float* out_scale = out + n;    // tuple output 1 (flat-concatenated)
    QParams* p       = (QParams*)d_ws;

    qparams_kernel<<<1, 1, 0, stream>>>(pre_sf, id_sf, xmin, xmax, p, out_scale);

    const int block = 256;
    int grid = 4096;               // 1M threads, 8 float4/thread
    int max_grid = (n4 + block - 1) / block;
    if (grid > max_grid) grid = max_grid;
    if (grid < 1) grid = 1;

    quantact_main<<<grid, block, 0, stream>>>(x, idn, (f32x4*)out, p, n4, n);
}

// Round 4
// 318.223 us; speedup vs baseline: 1.0586x; 1.0339x over previous
//
#include <hip/hip_runtime.h>
#include <math.h>

#define ACC_BITS 23

// Params computed once on-device (scalar inputs live in device memory).
struct QParams {
    float scale;
    int   fast;                       // 1 => 24-bit fast path valid
    int   nmx_hi, nmx_lo, Kx, srx12;  // x:  nm split 12/12, K=2^(sr-1), sr-12
    int   nmi_hi, nmi_lo, Ki, sri12;  // id: same
    long long nm_x64, nm_i64;         // generic fallback
    int   e_x, e_i;
};

__global__ void qparams_kernel(const float* __restrict__ pre_sf,
                               const float* __restrict__ id_sf,
                               const float* __restrict__ xminp,
                               const float* __restrict__ xmaxp,
                               QParams* __restrict__ p,
                               float* __restrict__ out_scale)
{
    float s = fmaxf(fmaxf(fabsf(xminp[0]), fabsf(xmaxp[0])), 1e-8f);
    float scale = s / 127.0f;                 // fp32 divide, bit-exact vs reference

    double s64  = (double)scale;
    double ns_x = (double)pre_sf[0] / s64;
    double ns_i = (double)id_sf[0] / s64;

    int e_x, e_i;
    double m_x = frexp(ns_x, &e_x);           // m in [0.5,1)
    double m_i = frexp(ns_i, &e_i);
    long long nm_x = (long long)rint(m_x * 8388608.0);   // round-half-even == jnp.round
    long long nm_i = (long long)rint(m_i * 8388608.0);

    p->scale  = scale;
    p->nm_x64 = nm_x;  p->e_x = e_x;
    p->nm_i64 = nm_i;  p->e_i = e_i;

    // Normalize nm == 2^23 -> (2^22, e+1). Result-identical: the rounded
    // numerator xi*nm + 2^(sr-1) is always even, so the -bit nudge cannot
    // cross a floor boundary differently between the two encodings.
    long long ax = nm_x, ai = nm_i;
    int ex = e_x, ei = e_i;
    if (ax == (1LL << 23)) { ax >>= 1; ex += 1; }
    if (ai == (1LL << 23)) { ai >>= 1; ei += 1; }
    int sr_x = ACC_BITS - ex, sr_i = ACC_BITS - ei;

    int fast = (ax > 0) && (ax < (1LL << 23)) &&
               (ai > 0) && (ai < (1LL << 23)) &&
               (sr_x >= 12) && (sr_x <= 30) && (sr_i >= 12) && (sr_i <= 30);
    p->fast = fast;
    p->nmx_hi = (int)(ax >> 12); p->nmx_lo = (int)(ax & 0xFFF);
    p->nmi_hi = (int)(ai >> 12); p->nmi_lo = (int)(ai & 0xFFF);
    p->Kx = fast ? (1 << (sr_x - 1)) : 0;
    p->Ki = fast ? (1 << (sr_i - 1)) : 0;
    p->srx12 = sr_x - 12;
    p->sri12 = sr_i - 12;

    *out_scale = scale;                       // tuple output 1
}

// Generic bit-exact replica (fallback + tail).
__device__ __forceinline__ long long fixed_point_mul64(long long xi, long long nm, int e) {
    long long tmp = xi * nm;
    if (e - ACC_BITS >= 0) {
        return tmp << (e - ACC_BITS);
    } else {
        int sr = ACC_BITS - e;
        long long nudge = (1LL << (sr - 1)) - (long long)(tmp < 0);
        return (tmp + nudge) >> sr;
    }
}

// Full-rate 24-bit-multiply fixed-point mul (bit-exact for |xi|<2^19,
// 0<nm<2^23, 12<=sr<=30; see R3 derivation).
__device__ __forceinline__ int fpm24(int xi, int nm_hi, int nm_lo, int K, int sr12) {
    int bit = (int)((unsigned)xi >> 31);
    int B = (__mul24(xi, nm_lo) + K - bit) >> 12;
    int A = __mul24(xi, nm_hi);
    return (A + B) >> sr12;
}

typedef float f32x4 __attribute__((ext_vector_type(4)));

#define TPB   256
#define VPT   4                      // float4 vectors per thread
#define TILE  (TPB * VPT)            // 1024 float4 per block

// One-shot block-tile kernel: each thread issues ALL 8 input loads before any
// use (8 KiB/wave outstanding) to maximize memory-level parallelism.
// R1/R3 grid-stride (4 loads then vmcnt(0)) plateaued at 118us latency-bound.
__global__ void __launch_bounds__(TPB)
quantact_main(const f32x4* __restrict__ x,
              const f32x4* __restrict__ idn,
              f32x4* __restrict__ out,
              const QParams* __restrict__ p,
              int n4, int n)
{
    const float scale = p->scale;
    const int base = blockIdx.x * TILE + threadIdx.x;

    if (p->fast) {
        const int nmx_hi = p->nmx_hi, nmx_lo = p->nmx_lo, Kx = p->Kx, srx = p->srx12;
        const int nmi_hi = p->nmi_hi, nmi_lo = p->nmi_lo, Ki = p->Ki, sri = p->sri12;

        if (base + (VPT - 1) * TPB < n4) {
            // full tile: 8 independent loads up front
            f32x4 xv[VPT], iv[VPT];
            #pragma unroll
            for (int k = 0; k < VPT; ++k) xv[k] = x[base + k * TPB];
            #pragma unroll
            for (int k = 0; k < VPT; ++k) iv[k] = idn[base + k * TPB];

            f32x4 ov[VPT];
            #pragma unroll
            for (int k = 0; k < VPT; ++k) {
                #pragma unroll
                for (int c = 0; c < 4; ++c) {
                    int o = fpm24((int)xv[k][c], nmx_hi, nmx_lo, Kx, srx)
                          + fpm24((int)iv[k][c], nmi_hi, nmi_lo, Ki, sri);
                    o = o < -128 ? -128 : (o > 127 ? 127 : o);   // v_med3_i32
                    ov[k][c] = (float)o * scale;
                }
            }
            #pragma unroll
            for (int k = 0; k < VPT; ++k) out[base + k * TPB] = ov[k];
        } else {
            #pragma unroll
            for (int k = 0; k < VPT; ++k) {
                int i = base + k * TPB;
                if (i < n4) {
                    f32x4 xv = x[i], iv = idn[i], ov;
                    #pragma unroll
                    for (int c = 0; c < 4; ++c) {
                        int o = fpm24((int)xv[c], nmx_hi, nmx_lo, Kx, srx)
                              + fpm24((int)iv[c], nmi_hi, nmi_lo, Ki, sri);
                        o = o < -128 ? -128 : (o > 127 ? 127 : o);
                        ov[c] = (float)o * scale;
                    }
                    out[i] = ov;
                }
            }
        }
    } else {
        // Generic path: exact 64-bit replica of the reference branches.
        const long long nm64_x = p->nm_x64, nm64_i = p->nm_i64;
        const int e_x = p->e_x, e_i = p->e_i;
        #pragma unroll
        for (int k = 0; k < VPT; ++k) {
            int i = base + k * TPB;
            if (i < n4) {
                f32x4 xv = x[i], iv = idn[i], ov;
                #pragma unroll
                for (int c = 0; c < 4; ++c) {
                    long long o = fixed_point_mul64((long long)xv[c], nm64_x, e_x)
                                + fixed_point_mul64((long long)iv[c], nm64_i, e_i);
                    o = o < -128 ? -128 : (o > 127 ? 127 : o);
                    ov[c] = (float)(int)o * scale;
                }
                out[i] = ov;
            }
        }
    }

    // scalar tail for n % 4 != 0 (not hit at this shape)
    if (blockIdx.x == 0) {
        const float* xs  = (const float*)x;
        const float* is_ = (const float*)idn;
        float* os = (float*)out;
        const long long nm64_x = p->nm_x64, nm64_i = p->nm_i64;
        const int e_x = p->e_x, e_i = p->e_i;
        for (int j = n4 * 4 + (int)threadIdx.x; j < n; j += TPB) {
            long long o = fixed_point_mul64((long long)xs[j], nm64_x, e_x)
                        + fixed_point_mul64((long long)is_[j], nm64_i, e_i);
            o = o < -128 ? -128 : (o > 127 ? 127 : o);
            os[j] = (float)(int)o * scale;
        }
    }
}

extern "C" void kernel_launch(void* const* d_in, const int* in_sizes, int n_in,
                              void* d_out, int out_size, void* d_ws, size_t ws_size,
                              hipStream_t stream) {
    const f32x4* x      = (const f32x4*)d_in[0];
    const f32x4* idn    = (const f32x4*)d_in[1];
    const float* pre_sf = (const float*)d_in[2];
    const float* id_sf  = (const float*)d_in[3];
    const float* xmin   = (const float*)d_in[4];
    const float* xmax   = (const float*)d_in[5];

    int n  = in_sizes[0];          // 33,554,432
    int n4 = n / 4;                // 8,388,608 float4

    float* out       = (float*)d_out;
    float* out_scale = out + n;    // tuple output 1 (flat-concatenated)
    QParams* p       = (QParams*)d_ws;

    qparams_kernel<<<1, 1, 0, stream>>>(pre_sf, id_sf, xmin, xmax, p, out_scale);

    int grid = (n4 + TILE - 1) / TILE;   // 8192 blocks, one-shot
    if (grid < 1) grid = 1;
    quantact_main<<<grid, TPB, 0, stream>>>(x, idn, (f32x4*)out, p, n4, n);
}